// Round 8
// baseline (212.704 us; speedup 1.0000x reference)
//
#include <hip/hip_runtime.h>
#include <hip/hip_bf16.h>
#include <hip/hip_fp16.h>

// MHAHead B=8,S=2048,E=512. R12 (resubmit; prior run died on infra).
//   R11 post-mortem: gemmS 124us = 277 TF, the m97 2-barrier loop's small-shape
//   regime -- staging latency fully exposed at the per-iter vmcnt(0) drain
//   (Mfma 11%, occ 30%: too few resident blocks to hide it).
//   R12: gemm_core 2-phase (T3-minimum): stage(next tile, buf^1) issued BEFORE
//   compute(buf[cur]); ONE __syncthreads per K-iter (its vmcnt drain lands
//   after ds_read+MFMA -> load latency hides under compute). LDS 16->32KB.
//   conv_w : weights/biases -> f16 in ws
//   conv_x : x fp32/bf16 -> f16 dense in ws (skipped if ws too small)
//   proj   : uni GEMM 128x128xBK32 (Q,K,Vt), all-gld16 staging
//   gemmS  : S = exp(mask? 0 : Q.K^T*scale) f16, in-kernel mask pack, phased
//   gemmO  : out = (S @ Vt) / rowsum(S), rowsum via all-ones-B MFMA column

typedef unsigned short u16;
typedef unsigned long long u64;
typedef __attribute__((ext_vector_type(8))) short short8;
typedef __attribute__((ext_vector_type(8))) _Float16 half8;
typedef __attribute__((ext_vector_type(4))) float float4v;

#define S_DIM 2048
#define E_DIM 512
#define NROWS (8 * S_DIM)
#define SCALE 0.044194173824159216f

__device__ __forceinline__ float4v mfma16(short8 a, short8 b, float4v c) {
    return __builtin_amdgcn_mfma_f32_16x16x32_f16(
        __builtin_bit_cast(half8, a), __builtin_bit_cast(half8, b), c, 0, 0, 0);
}
__device__ __forceinline__ float bf2f(unsigned int u) {
    union { unsigned int i; float f; } v; v.i = u << 16; return v.f;
}
__device__ __forceinline__ u16 f2h_bits(float f) {
    union { _Float16 h; u16 u; } v; v.h = (_Float16)f; return v.u;
}
__device__ __forceinline__ float h2f(u16 u) {
    union { u16 u; _Float16 h; } v; v.u = u; return (float)v.h;
}
__device__ __forceinline__ int detect_bf16(const void* wp) {
    const u16* w = (const u16*)wp;
    int cnt = 0;
    for (int i = 0; i < 64; ++i) {
        int e = (w[2 * i] >> 7) & 0xff;
        cnt += (e >= 100 && e <= 131) ? 1 : 0;
    }
    return cnt >= 40;
}
__device__ __forceinline__ void load8(const void* base, size_t idx, int isbf, float* f) {
    if (isbf) {
        uint4 v = *(const uint4*)((const u16*)base + idx);
        f[0] = bf2f(v.x & 0xffffu); f[1] = bf2f(v.x >> 16);
        f[2] = bf2f(v.y & 0xffffu); f[3] = bf2f(v.y >> 16);
        f[4] = bf2f(v.z & 0xffffu); f[5] = bf2f(v.z >> 16);
        f[6] = bf2f(v.w & 0xffffu); f[7] = bf2f(v.w >> 16);
    } else {
        const float* p = (const float*)base + idx;
        float4 a = *(const float4*)p;
        float4 b = *(const float4*)(p + 4);
        f[0] = a.x; f[1] = a.y; f[2] = a.z; f[3] = a.w;
        f[4] = b.x; f[5] = b.y; f[6] = b.z; f[7] = b.w;
    }
}
__device__ __forceinline__ float load1(const void* base, size_t idx, int isbf) {
    return isbf ? bf2f(((const u16*)base)[idx]) : ((const float*)base)[idx];
}

// async 16B global -> LDS (per-lane src, wave-uniform LDS base + lane*16)
__device__ __forceinline__ void gld16(const u16* g, u16* l) {
    __builtin_amdgcn_global_load_lds(
        (const __attribute__((address_space(1))) void*)g,
        (__attribute__((address_space(3))) void*)l, 16, 0, 0);
}

// stage one 16B granule into LDS. C=0: f16 global, async gld16.
// C=1: fp32 global -> f16 (reg-staged). C=2: bf16 global -> f16 (reg-staged).
template<int C>
__device__ __forceinline__ void stage(const void* g, size_t off, u16* lds) {
    if constexpr (C == 0) {
        gld16((const u16*)g + off, lds);
    } else if constexpr (C == 1) {
        const float* p = (const float*)g + off;
        float4 a = *(const float4*)p;
        float4 b = *(const float4*)(p + 4);
        union { u16 h[8]; short8 v; } pk;
        pk.h[0] = f2h_bits(a.x); pk.h[1] = f2h_bits(a.y);
        pk.h[2] = f2h_bits(a.z); pk.h[3] = f2h_bits(a.w);
        pk.h[4] = f2h_bits(b.x); pk.h[5] = f2h_bits(b.y);
        pk.h[6] = f2h_bits(b.z); pk.h[7] = f2h_bits(b.w);
        *(short8*)lds = pk.v;
    } else {
        uint4 v = *(const uint4*)((const u16*)g + off);
        unsigned int uu[4] = {v.x, v.y, v.z, v.w};
        union { u16 h[8]; short8 v8; } pk;
#pragma unroll
        for (int j = 0; j < 4; ++j) {
            pk.h[2 * j]     = f2h_bits(bf2f(uu[j] & 0xffffu));
            pk.h[2 * j + 1] = f2h_bits(bf2f(uu[j] >> 16));
        }
        *(short8*)lds = pk.v8;
    }
}

// ---------------- conversion kernels (read inputs, write ws) ----------------
__global__ __launch_bounds__(256) void conv_w(
    const void* w0, const void* w1, const void* w2,
    const void* b0, const void* b1, const void* b2, u16* wb)
{
    const int z = blockIdx.y;
    const void* w = (z == 0) ? w0 : (z == 1) ? w1 : w2;
    const void* bb = (z == 0) ? b0 : (z == 1) ? b1 : b2;
    const int isbf = detect_bf16(w0);
    const size_t idx = ((size_t)blockIdx.x * 256 + threadIdx.x) * 8;
    float f[8];
    load8(w, idx, isbf, f);
    union { u16 h[8]; uint4 v; } pk;
#pragma unroll
    for (int j = 0; j < 8; ++j) pk.h[j] = f2h_bits(f[j]);
    *(uint4*)(wb + (size_t)z * 262144 + idx) = pk.v;
    if (blockIdx.x == 0) {
        u16* bbase = wb + 3 * 262144 + z * 512;
#pragma unroll
        for (int j = 0; j < 2; ++j) {
            int i = threadIdx.x * 2 + j;
            bbase[i] = f2h_bits(load1(bb, i, isbf));
        }
    }
}

// x fp32/bf16 -> f16 dense [16384][512] in ws. One wave per row.
__global__ __launch_bounds__(256) void conv_x(
    const void* x, const void* wq_orig, u16* xh)
{
    const int w = threadIdx.x >> 6, l = threadIdx.x & 63;
    const int row = blockIdx.x * 4 + w;
    union { u16 h[8]; uint4 v; } pk;
    if (detect_bf16(wq_orig)) {
        uint4 v = *(const uint4*)((const u16*)x + (size_t)row * 512 + l * 8);
        unsigned int uu[4] = {v.x, v.y, v.z, v.w};
#pragma unroll
        for (int j = 0; j < 4; ++j) {
            pk.h[2 * j]     = f2h_bits(bf2f(uu[j] & 0xffffu));
            pk.h[2 * j + 1] = f2h_bits(bf2f(uu[j] >> 16));
        }
    } else {
        const float* src = (const float*)x + (size_t)row * 512 + l * 8;
        float4 a = *(const float4*)src;
        float4 b = *(const float4*)(src + 4);
        pk.h[0] = f2h_bits(a.x); pk.h[1] = f2h_bits(a.y);
        pk.h[2] = f2h_bits(a.z); pk.h[3] = f2h_bits(a.w);
        pk.h[4] = f2h_bits(b.x); pk.h[5] = f2h_bits(b.y);
        pk.h[6] = f2h_bits(b.z); pk.h[7] = f2h_bits(b.w);
    }
    *(uint4*)(xh + (size_t)row * 512 + l * 8) = pk.v;
}

// ---------------- shared GEMM core (2-phase double-buffered) ----------------
// 128x128 tile, BK=32, 4 waves (2x2 of 64x64). Per K-iter: issue next-tile
// stage into buf^1, compute buf[cur], ONE __syncthreads (drains vmcnt after
// compute -> staging latency hidden). LDS: As/Bs = 2 x 4096 u16 each.
// Granule layout within a buffer: flat = 4*r + (kq ^ ((r>>1)&3)), 2-way max.
template<int ONES, int CA, int CB>
__device__ __forceinline__ void gemm_core(
    const void* __restrict__ A, int sA, const void* __restrict__ B, int sB, int K,
    u16* As, u16* Bs, float4v acc[4][4], float4v accS[4])
{
    const int t = threadIdx.x;
    const int w = t >> 6, l = t & 63;
    const int lane15 = l & 15, quad = l >> 4;
    const int wm = w & 1, wn = w >> 1;

    short8 ones;
#pragma unroll
    for (int j = 0; j < 8; ++j) ones[j] = (short)0x3C00;   // f16 1.0

    auto stage_tile = [&](int kt, int bo) {
#pragma unroll
        for (int i = 0; i < 2; ++i) {
            const int fg = w * 128 + i * 64 + l;
            const int r = fg >> 2;
            const int kq = (fg & 3) ^ ((r >> 1) & 3);
            stage<CA>(A, (size_t)r * sA + kt + kq * 8, As + bo + fg * 8);
            stage<CB>(B, (size_t)r * sB + kt + kq * 8, Bs + bo + fg * 8);
        }
    };

    stage_tile(0, 0);
    __syncthreads();                 // full drain: buf0 ready
    int cur = 0;
    for (int kt = 0; kt < K; kt += 32) {
        if (kt + 32 < K) stage_tile(kt + 32, (cur ^ 1) * 4096);  // async overlap
        const int bo = cur * 4096;

        short8 af[4], bf[4];
#pragma unroll
        for (int mi = 0; mi < 4; ++mi) {
            const int r = wm * 64 + mi * 16 + lane15;
            af[mi] = *(const short8*)&As[bo + (4 * r + (quad ^ ((r >> 1) & 3))) * 8];
        }
#pragma unroll
        for (int ni = 0; ni < 4; ++ni) {
            const int r = wn * 64 + ni * 16 + lane15;
            bf[ni] = *(const short8*)&Bs[bo + (4 * r + (quad ^ ((r >> 1) & 3))) * 8];
        }
#pragma unroll
        for (int mi = 0; mi < 4; ++mi) {
#pragma unroll
            for (int ni = 0; ni < 4; ++ni)
                acc[mi][ni] = mfma16(af[mi], bf[ni], acc[mi][ni]);
            if (ONES) accS[mi] = mfma16(af[mi], ones, accS[mi]);
        }
        __syncthreads();             // drains next-tile loads; frees buf[cur]
        cur ^= 1;
    }
}

#define GEMM_PRE()                                                     \
    __shared__ u16 As[8192] __attribute__((aligned(16)));              \
    __shared__ u16 Bs[8192] __attribute__((aligned(16)));              \
    const int t = threadIdx.x;                                         \
    const int w = t >> 6, l = t & 63;                                  \
    const int lane15 = l & 15, quad = l >> 4;                          \
    const int wm = w & 1, wn = w >> 1;                                 \
    (void)l; (void)w;                                                  \
    float4v acc[4][4];                                                 \
    float4v accS[4];                                                   \
    _Pragma("unroll") for (int mi = 0; mi < 4; ++mi) {                 \
        accS[mi] = (float4v){0.f, 0.f, 0.f, 0.f};                      \
        _Pragma("unroll") for (int ni = 0; ni < 4; ++ni)               \
            acc[mi][ni] = (float4v){0.f, 0.f, 0.f, 0.f};               \
    }

// ---------------- proj: Q, K, Vt (pure GEMM, no mask) ----------------
// XM: 0 = xh f16 (gld16 both sides), 1 = x fp32, 2 = x bf16.
// z<2: A = x[m0..], B = wb[z][n0..]; C -> Q or K (f16, ws)
// z=2: A = wb[2][m0..], B = x[n0..]; C -> Vt (f16, ws)
template<int XM>
__global__ __launch_bounds__(256) void proj_gemm(
    const void* __restrict__ xsrc, const u16* __restrict__ wb,
    u16* __restrict__ qb, u16* __restrict__ kb, u16* __restrict__ vt)
{
    GEMM_PRE();
    const int z = blockIdx.z;
    // T1 XCD swizzle within the 512-plane (nwg %8==0, bijective)
    const int hh = blockIdx.y * 4 + blockIdx.x;
    const int sl = (hh & 7) * 64 + (hh >> 3);
    const int ty = sl >> 2, tx = sl & 3;
    const u16* bias = wb + 3 * 262144 + z * 512;

    int m0, n0;
    if (z < 2) { m0 = ty * 128; n0 = tx * 128; }
    else       { m0 = tx * 128; n0 = ty * 128; }

    if (z < 2) {
        const void* B = wb + (size_t)z * 262144 + (size_t)n0 * 512;
        const void* A = (XM == 1)
            ? (const void*)((const float*)xsrc + (size_t)m0 * 512)
            : (const void*)((const u16*)xsrc + (size_t)m0 * 512);
        gemm_core<0, XM == 0 ? 0 : XM, 0>(A, 512, B, 512, 512, As, Bs, acc, accS);
    } else {
        const void* A = wb + (size_t)2 * 262144 + (size_t)m0 * 512;
        const void* B = (XM == 1)
            ? (const void*)((const float*)xsrc + (size_t)n0 * 512)
            : (const void*)((const u16*)xsrc + (size_t)n0 * 512);
        gemm_core<0, 0, XM == 0 ? 0 : XM>(A, 512, B, 512, 512, As, Bs, acc, accS);
    }

    if (z < 2) {
        u16* dst = z ? kb : qb;
        float bcol[4];
#pragma unroll
        for (int ni = 0; ni < 4; ++ni)
            bcol[ni] = h2f(bias[n0 + wn * 64 + ni * 16 + lane15]);
#pragma unroll
        for (int mi = 0; mi < 4; ++mi)
#pragma unroll
            for (int ni = 0; ni < 4; ++ni)
#pragma unroll
                for (int r = 0; r < 4; ++r) {
                    const int row = m0 + wm * 64 + mi * 16 + quad * 4 + r;
                    const int col = n0 + wn * 64 + ni * 16 + lane15;
                    dst[(size_t)row * 512 + col] = f2h_bits(acc[mi][ni][r] + bcol[ni]);
                }
    } else {
#pragma unroll
        for (int mi = 0; mi < 4; ++mi)
#pragma unroll
            for (int r = 0; r < 4; ++r) {
                const int e = m0 + wm * 64 + mi * 16 + quad * 4 + r;      // 0..511
                const float bias_e = h2f(bias[e]);
#pragma unroll
                for (int ni = 0; ni < 4; ++ni) {
                    const int tok = n0 + wn * 64 + ni * 16 + lane15;
                    vt[((size_t)(tok >> 11) * 512 + e) * 2048 + (tok & 2047)] =
                        f2h_bits(acc[mi][ni][r] + bias_e);
                }
            }
    }
}

// ---------------- gemmS: S = exp(masked(Q.K^T * scale)) f16, phased ----------
// Prologue: each wave ballot-packs its 64x64 mask quadrant (4 rounds of 16
// coalesced 256B loads, held in flight) into 64 u64 LDS words. Epilogue reads
// broadcast LDS bits -- no global mask access at tile end.
__global__ __launch_bounds__(256) void gemmS(
    const u16* __restrict__ qb, const u16* __restrict__ kb,
    const int* __restrict__ mask, u16* __restrict__ Sdst, int b0)
{
    GEMM_PRE();
    __shared__ u64 maskw[256];          // [wave][row_local]
    const int zb = blockIdx.z;
    const int b = b0 + zb;
    // T1 XCD swizzle: plane nwg=256
    const int hh = blockIdx.y * 16 + blockIdx.x;
    const int sl = (hh & 7) * 32 + (hh >> 3);
    const int m0 = (sl >> 4) * 128, n0 = (sl & 15) * 128;

    {   // mask pack: wave (wm,wn) covers rows m0+wm*64.., cols n0+wn*64..
        const int* mrow = mask + ((size_t)b * S_DIM + m0 + wm * 64) * S_DIM
                               + n0 + wn * 64 + l;
#pragma unroll
        for (int rnd = 0; rnd < 4; ++rnd) {
            int v[16];
#pragma unroll
            for (int i = 0; i < 16; ++i)
                v[i] = mrow[(size_t)(rnd * 16 + i) * S_DIM];
            u64 bb[16];
#pragma unroll
            for (int i = 0; i < 16; ++i)
                bb[i] = __ballot(v[i] > 0);
            if (l == 0) {
#pragma unroll
                for (int i = 0; i < 16; ++i)
                    maskw[w * 64 + rnd * 16 + i] = bb[i];
            }
        }
    }

    const u16* A = qb + (size_t)(b * S_DIM + m0) * 512;
    const u16* B = kb + (size_t)(b * S_DIM + n0) * 512;
    gemm_core<0, 0, 0>(A, 512, B, 512, 512, As, Bs, acc, accS);

    u16* Sb = Sdst + (size_t)zb * S_DIM * S_DIM;
#pragma unroll
    for (int mi = 0; mi < 4; ++mi)
#pragma unroll
        for (int r = 0; r < 4; ++r) {
            const int row = m0 + wm * 64 + mi * 16 + quad * 4 + r;
            const u64 wbits = maskw[w * 64 + mi * 16 + quad * 4 + r];
            const int col0 = n0 + wn * 64 + lane15;
#pragma unroll
            for (int ni = 0; ni < 4; ++ni) {
                const int masked = (int)((wbits >> (lane15 + ni * 16)) & 1);
                const float p = masked ? 0.f : __expf(acc[mi][ni][r] * SCALE);
                Sb[(size_t)row * S_DIM + col0 + ni * 16] = f2h_bits(p);
            }
        }
}

// ---------------- gemmO: out = (S @ Vt) / rowsum(S), phased ----------------
__global__ __launch_bounds__(256) void gemmO(
    const u16* __restrict__ Ssrc, const u16* __restrict__ vt,
    float* __restrict__ outp, int b0)
{
    GEMM_PRE();
    const int zb = blockIdx.z;
    const int b = b0 + zb;
    // T1 XCD swizzle: plane nwg=64
    const int hh = blockIdx.y * 4 + blockIdx.x;
    const int sl = (hh & 7) * 8 + (hh >> 3);
    const int m0 = (sl >> 2) * 128, n0 = (sl & 3) * 128;
    const u16* A = Ssrc + (size_t)zb * S_DIM * S_DIM + (size_t)m0 * S_DIM;
    const u16* B = vt + ((size_t)b * 512 + n0) * 2048;

    gemm_core<1, 0, 0>(A, S_DIM, B, S_DIM, S_DIM, As, Bs, acc, accS);

#pragma unroll
    for (int mi = 0; mi < 4; ++mi)
#pragma unroll
        for (int r = 0; r < 4; ++r) {
            const int row = m0 + wm * 64 + mi * 16 + quad * 4 + r;
            const float inv = 1.f / accS[mi][r];
#pragma unroll
            for (int ni = 0; ni < 4; ++ni) {
                const int col = n0 + wn * 64 + ni * 16 + lane15;
                outp[((size_t)b * S_DIM + row) * E_DIM + col] = acc[mi][ni][r] * inv;
            }
        }
}

extern "C" void kernel_launch(void* const* d_in, const int* in_sizes, int n_in,
                              void* d_out, int out_size, void* d_ws, size_t ws_size,
                              hipStream_t stream) {
    const void* x    = d_in[0];
    const int*  mask = (const int*)d_in[1];
    const void* wq   = d_in[2];
    const void* bq   = d_in[3];
    const void* wk   = d_in[4];
    const void* bk   = d_in[5];
    const void* wv   = d_in[6];
    const void* bv   = d_in[7];

    const size_t MB   = 1ull << 20;
    const size_t QSZ  = (size_t)NROWS * E_DIM;          // u16 elems per Q/K/Vt/xh
    const size_t S_PB = (size_t)S_DIM * S_DIM;          // u16 elems per S batch

    u16* wb   = (u16*)d_ws;                             // 2 MB (weights+bias f16)
    u16* qb   = (u16*)((char*)d_ws + 2 * MB);
    u16* kb   = qb + QSZ;
    u16* vtb  = kb + QSZ;
    u16* xh   = vtb + QSZ;                              // 16.8 MB f16 x (dead after proj)
    u16* sS   = xh;                                     // S scratch aliases xh

    const size_t fixed = 2 * MB + 3 * QSZ * 2;          // 52.4 MB (pre-xh)
    const size_t avail = (ws_size > fixed) ? (ws_size - fixed) : 0;
    const int use_xh = avail >= (QSZ * 2 + 2 * S_PB);   // xh + >=2 S batches
    const size_t availB = avail / (S_PB * 2);
    const int P = (availB >= 8) ? 8 : (availB >= 4) ? 4 : (availB >= 2) ? 2 : 1;

    conv_w<<<dim3(128, 3), 256, 0, stream>>>(wq, wk, wv, bq, bk, bv, wb);

    if (use_xh) {
        conv_x<<<NROWS / 4, 256, 0, stream>>>(x, wq, xh);
        proj_gemm<0><<<dim3(4, 128, 3), 256, 0, stream>>>(xh, wb, qb, kb, vtb);
    } else {
        // small-ws fallback: on-the-fly x conversion; dtype via in_sizes
        // (x fp32 = NROWS*512*4 bytes; 16-bit input = half that).
        if (in_sizes[0] >= (int)(NROWS * 512 * 4))
            proj_gemm<1><<<dim3(4, 128, 3), 256, 0, stream>>>(x, wb, qb, kb, vtb);
        else
            proj_gemm<2><<<dim3(4, 128, 3), 256, 0, stream>>>(x, wb, qb, kb, vtb);
    }

    for (int p = 0; p < 8; p += P) {
        gemmS<<<dim3(16, 16, P), 256, 0, stream>>>(qb, kb, mask, sS, p);
        gemmO<<<dim3(4, 16, P), 256, 0, stream>>>(sS, vtb, (float*)d_out, p);
    }
}

// Round 9
// 202.067 us; speedup vs baseline: 1.0526x; 1.0526x over previous
//
#include <hip/hip_runtime.h>
#include <hip/hip_bf16.h>
#include <hip/hip_fp16.h>

// MHAHead B=8,S=2048,E=512. R13: R11 core + BK=64 single-buffered K-loop.
//   R12 post-mortem: 2-phase dbuf REGRESSED (gemmS 124->130) -- syncthreads'
//   vmcnt(0) drains the just-issued next-tile loads (m99/m100 reproduced).
//   R13: revert to R11's 2-barrier structure but BK=64: per barrier-pair
//   8 gld16/wave in flight (2x MLP) and 40 MFMA (2x compute), half the drains.
//   LDS 32KB (+2KB mask in gemmS) keeps 4 blocks/CU; occupancy unchanged.
//   conv_w : weights/biases -> f16 in ws
//   conv_x : x fp32/bf16 -> f16 dense in ws (skipped if ws too small)
//   proj   : uni GEMM 128x128xBK64 (Q,K,Vt), all-gld16 staging
//   gemmS  : S = exp(mask? 0 : Q.K^T*scale) f16, in-kernel mask pack, phased
//   gemmO  : out = (S @ Vt) / rowsum(S), rowsum via all-ones-B MFMA column

typedef unsigned short u16;
typedef unsigned long long u64;
typedef __attribute__((ext_vector_type(8))) short short8;
typedef __attribute__((ext_vector_type(8))) _Float16 half8;
typedef __attribute__((ext_vector_type(4))) float float4v;

#define S_DIM 2048
#define E_DIM 512
#define NROWS (8 * S_DIM)
#define SCALE 0.044194173824159216f

__device__ __forceinline__ float4v mfma16(short8 a, short8 b, float4v c) {
    return __builtin_amdgcn_mfma_f32_16x16x32_f16(
        __builtin_bit_cast(half8, a), __builtin_bit_cast(half8, b), c, 0, 0, 0);
}
__device__ __forceinline__ float bf2f(unsigned int u) {
    union { unsigned int i; float f; } v; v.i = u << 16; return v.f;
}
__device__ __forceinline__ u16 f2h_bits(float f) {
    union { _Float16 h; u16 u; } v; v.h = (_Float16)f; return v.u;
}
__device__ __forceinline__ float h2f(u16 u) {
    union { u16 u; _Float16 h; } v; v.u = u; return (float)v.h;
}
__device__ __forceinline__ int detect_bf16(const void* wp) {
    const u16* w = (const u16*)wp;
    int cnt = 0;
    for (int i = 0; i < 64; ++i) {
        int e = (w[2 * i] >> 7) & 0xff;
        cnt += (e >= 100 && e <= 131) ? 1 : 0;
    }
    return cnt >= 40;
}
__device__ __forceinline__ void load8(const void* base, size_t idx, int isbf, float* f) {
    if (isbf) {
        uint4 v = *(const uint4*)((const u16*)base + idx);
        f[0] = bf2f(v.x & 0xffffu); f[1] = bf2f(v.x >> 16);
        f[2] = bf2f(v.y & 0xffffu); f[3] = bf2f(v.y >> 16);
        f[4] = bf2f(v.z & 0xffffu); f[5] = bf2f(v.z >> 16);
        f[6] = bf2f(v.w & 0xffffu); f[7] = bf2f(v.w >> 16);
    } else {
        const float* p = (const float*)base + idx;
        float4 a = *(const float4*)p;
        float4 b = *(const float4*)(p + 4);
        f[0] = a.x; f[1] = a.y; f[2] = a.z; f[3] = a.w;
        f[4] = b.x; f[5] = b.y; f[6] = b.z; f[7] = b.w;
    }
}
__device__ __forceinline__ float load1(const void* base, size_t idx, int isbf) {
    return isbf ? bf2f(((const u16*)base)[idx]) : ((const float*)base)[idx];
}

// async 16B global -> LDS (per-lane src, wave-uniform LDS base + lane*16)
__device__ __forceinline__ void gld16(const u16* g, u16* l) {
    __builtin_amdgcn_global_load_lds(
        (const __attribute__((address_space(1))) void*)g,
        (__attribute__((address_space(3))) void*)l, 16, 0, 0);
}

// stage one 16B granule into LDS. C=0: f16 global, async gld16.
// C=1: fp32 global -> f16 (reg-staged). C=2: bf16 global -> f16 (reg-staged).
template<int C>
__device__ __forceinline__ void stage(const void* g, size_t off, u16* lds) {
    if constexpr (C == 0) {
        gld16((const u16*)g + off, lds);
    } else if constexpr (C == 1) {
        const float* p = (const float*)g + off;
        float4 a = *(const float4*)p;
        float4 b = *(const float4*)(p + 4);
        union { u16 h[8]; short8 v; } pk;
        pk.h[0] = f2h_bits(a.x); pk.h[1] = f2h_bits(a.y);
        pk.h[2] = f2h_bits(a.z); pk.h[3] = f2h_bits(a.w);
        pk.h[4] = f2h_bits(b.x); pk.h[5] = f2h_bits(b.y);
        pk.h[6] = f2h_bits(b.z); pk.h[7] = f2h_bits(b.w);
        *(short8*)lds = pk.v;
    } else {
        uint4 v = *(const uint4*)((const u16*)g + off);
        unsigned int uu[4] = {v.x, v.y, v.z, v.w};
        union { u16 h[8]; short8 v8; } pk;
#pragma unroll
        for (int j = 0; j < 4; ++j) {
            pk.h[2 * j]     = f2h_bits(bf2f(uu[j] & 0xffffu));
            pk.h[2 * j + 1] = f2h_bits(bf2f(uu[j] >> 16));
        }
        *(short8*)lds = pk.v8;
    }
}

// ---------------- conversion kernels (read inputs, write ws) ----------------
__global__ __launch_bounds__(256) void conv_w(
    const void* w0, const void* w1, const void* w2,
    const void* b0, const void* b1, const void* b2, u16* wb)
{
    const int z = blockIdx.y;
    const void* w = (z == 0) ? w0 : (z == 1) ? w1 : w2;
    const void* bb = (z == 0) ? b0 : (z == 1) ? b1 : b2;
    const int isbf = detect_bf16(w0);
    const size_t idx = ((size_t)blockIdx.x * 256 + threadIdx.x) * 8;
    float f[8];
    load8(w, idx, isbf, f);
    union { u16 h[8]; uint4 v; } pk;
#pragma unroll
    for (int j = 0; j < 8; ++j) pk.h[j] = f2h_bits(f[j]);
    *(uint4*)(wb + (size_t)z * 262144 + idx) = pk.v;
    if (blockIdx.x == 0) {
        u16* bbase = wb + 3 * 262144 + z * 512;
#pragma unroll
        for (int j = 0; j < 2; ++j) {
            int i = threadIdx.x * 2 + j;
            bbase[i] = f2h_bits(load1(bb, i, isbf));
        }
    }
}

// x fp32/bf16 -> f16 dense [16384][512] in ws. One wave per row.
__global__ __launch_bounds__(256) void conv_x(
    const void* x, const void* wq_orig, u16* xh)
{
    const int w = threadIdx.x >> 6, l = threadIdx.x & 63;
    const int row = blockIdx.x * 4 + w;
    union { u16 h[8]; uint4 v; } pk;
    if (detect_bf16(wq_orig)) {
        uint4 v = *(const uint4*)((const u16*)x + (size_t)row * 512 + l * 8);
        unsigned int uu[4] = {v.x, v.y, v.z, v.w};
#pragma unroll
        for (int j = 0; j < 4; ++j) {
            pk.h[2 * j]     = f2h_bits(bf2f(uu[j] & 0xffffu));
            pk.h[2 * j + 1] = f2h_bits(bf2f(uu[j] >> 16));
        }
    } else {
        const float* src = (const float*)x + (size_t)row * 512 + l * 8;
        float4 a = *(const float4*)src;
        float4 b = *(const float4*)(src + 4);
        pk.h[0] = f2h_bits(a.x); pk.h[1] = f2h_bits(a.y);
        pk.h[2] = f2h_bits(a.z); pk.h[3] = f2h_bits(a.w);
        pk.h[4] = f2h_bits(b.x); pk.h[5] = f2h_bits(b.y);
        pk.h[6] = f2h_bits(b.z); pk.h[7] = f2h_bits(b.w);
    }
    *(uint4*)(xh + (size_t)row * 512 + l * 8) = pk.v;
}

// ---------------- shared GEMM core (BK=64, single-buffered) ----------------
// 128x128 tile, 4 waves (2x2 of 64x64). Per K-iter (64 wide): stage both
// 32-wide halves (8 gld16/wave in flight -> 2x MLP), one drain barrier,
// then 2x(16+ONES*4) MFMA. Half the barrier count of BK=32.
// Granule layout per half: flat = 4*r + (kq ^ ((r>>1)&3)), 2-way max conflict.
template<int ONES, int CA, int CB>
__device__ __forceinline__ void gemm_core(
    const void* __restrict__ A, int sA, const void* __restrict__ B, int sB, int K,
    u16* As, u16* Bs, float4v acc[4][4], float4v accS[4])
{
    const int t = threadIdx.x;
    const int w = t >> 6, l = t & 63;
    const int lane15 = l & 15, quad = l >> 4;
    const int wm = w & 1, wn = w >> 1;

    short8 ones;
#pragma unroll
    for (int j = 0; j < 8; ++j) ones[j] = (short)0x3C00;   // f16 1.0

    for (int kt = 0; kt < K; kt += 64) {
        __syncthreads();                 // frees buffer from previous compute
#pragma unroll
        for (int h = 0; h < 2; ++h)
#pragma unroll
            for (int i = 0; i < 2; ++i) {
                const int fg = w * 128 + i * 64 + l;
                const int r = fg >> 2;
                const int kq = (fg & 3) ^ ((r >> 1) & 3);
                stage<CA>(A, (size_t)r * sA + kt + 32 * h + kq * 8,
                          As + h * 4096 + fg * 8);
                stage<CB>(B, (size_t)r * sB + kt + 32 * h + kq * 8,
                          Bs + h * 4096 + fg * 8);
            }
        __syncthreads();                 // single drain per 64-wide K step

#pragma unroll
        for (int h = 0; h < 2; ++h) {
            const int bo = h * 4096;
            short8 af[4], bf[4];
#pragma unroll
            for (int mi = 0; mi < 4; ++mi) {
                const int r = wm * 64 + mi * 16 + lane15;
                af[mi] = *(const short8*)&As[bo + (4 * r + (quad ^ ((r >> 1) & 3))) * 8];
            }
#pragma unroll
            for (int ni = 0; ni < 4; ++ni) {
                const int r = wn * 64 + ni * 16 + lane15;
                bf[ni] = *(const short8*)&Bs[bo + (4 * r + (quad ^ ((r >> 1) & 3))) * 8];
            }
#pragma unroll
            for (int mi = 0; mi < 4; ++mi) {
#pragma unroll
                for (int ni = 0; ni < 4; ++ni)
                    acc[mi][ni] = mfma16(af[mi], bf[ni], acc[mi][ni]);
                if (ONES) accS[mi] = mfma16(af[mi], ones, accS[mi]);
            }
        }
    }
}

#define GEMM_PRE()                                                     \
    __shared__ u16 As[8192] __attribute__((aligned(16)));              \
    __shared__ u16 Bs[8192] __attribute__((aligned(16)));              \
    const int t = threadIdx.x;                                         \
    const int w = t >> 6, l = t & 63;                                  \
    const int lane15 = l & 15, quad = l >> 4;                          \
    const int wm = w & 1, wn = w >> 1;                                 \
    (void)l; (void)w;                                                  \
    float4v acc[4][4];                                                 \
    float4v accS[4];                                                   \
    _Pragma("unroll") for (int mi = 0; mi < 4; ++mi) {                 \
        accS[mi] = (float4v){0.f, 0.f, 0.f, 0.f};                      \
        _Pragma("unroll") for (int ni = 0; ni < 4; ++ni)               \
            acc[mi][ni] = (float4v){0.f, 0.f, 0.f, 0.f};               \
    }

// ---------------- proj: Q, K, Vt (pure GEMM, no mask) ----------------
// XM: 0 = xh f16 (gld16 both sides), 1 = x fp32, 2 = x bf16.
// z<2: A = x[m0..], B = wb[z][n0..]; C -> Q or K (f16, ws)
// z=2: A = wb[2][m0..], B = x[n0..]; C -> Vt (f16, ws)
template<int XM>
__global__ __launch_bounds__(256) void proj_gemm(
    const void* __restrict__ xsrc, const u16* __restrict__ wb,
    u16* __restrict__ qb, u16* __restrict__ kb, u16* __restrict__ vt)
{
    GEMM_PRE();
    const int z = blockIdx.z;
    // T1 XCD swizzle within the 512-plane (nwg %8==0, bijective)
    const int hh = blockIdx.y * 4 + blockIdx.x;
    const int sl = (hh & 7) * 64 + (hh >> 3);
    const int ty = sl >> 2, tx = sl & 3;
    const u16* bias = wb + 3 * 262144 + z * 512;

    int m0, n0;
    if (z < 2) { m0 = ty * 128; n0 = tx * 128; }
    else       { m0 = tx * 128; n0 = ty * 128; }

    if (z < 2) {
        const void* B = wb + (size_t)z * 262144 + (size_t)n0 * 512;
        const void* A = (XM == 1)
            ? (const void*)((const float*)xsrc + (size_t)m0 * 512)
            : (const void*)((const u16*)xsrc + (size_t)m0 * 512);
        gemm_core<0, XM == 0 ? 0 : XM, 0>(A, 512, B, 512, 512, As, Bs, acc, accS);
    } else {
        const void* A = wb + (size_t)2 * 262144 + (size_t)m0 * 512;
        const void* B = (XM == 1)
            ? (const void*)((const float*)xsrc + (size_t)n0 * 512)
            : (const void*)((const u16*)xsrc + (size_t)n0 * 512);
        gemm_core<0, 0, XM == 0 ? 0 : XM>(A, 512, B, 512, 512, As, Bs, acc, accS);
    }

    if (z < 2) {
        u16* dst = z ? kb : qb;
        float bcol[4];
#pragma unroll
        for (int ni = 0; ni < 4; ++ni)
            bcol[ni] = h2f(bias[n0 + wn * 64 + ni * 16 + lane15]);
#pragma unroll
        for (int mi = 0; mi < 4; ++mi)
#pragma unroll
            for (int ni = 0; ni < 4; ++ni)
#pragma unroll
                for (int r = 0; r < 4; ++r) {
                    const int row = m0 + wm * 64 + mi * 16 + quad * 4 + r;
                    const int col = n0 + wn * 64 + ni * 16 + lane15;
                    dst[(size_t)row * 512 + col] = f2h_bits(acc[mi][ni][r] + bcol[ni]);
                }
    } else {
#pragma unroll
        for (int mi = 0; mi < 4; ++mi)
#pragma unroll
            for (int r = 0; r < 4; ++r) {
                const int e = m0 + wm * 64 + mi * 16 + quad * 4 + r;      // 0..511
                const float bias_e = h2f(bias[e]);
#pragma unroll
                for (int ni = 0; ni < 4; ++ni) {
                    const int tok = n0 + wn * 64 + ni * 16 + lane15;
                    vt[((size_t)(tok >> 11) * 512 + e) * 2048 + (tok & 2047)] =
                        f2h_bits(acc[mi][ni][r] + bias_e);
                }
            }
    }
}

// ---------------- gemmS: S = exp(masked(Q.K^T * scale)) f16, phased ----------
// Prologue: each wave ballot-packs its 64x64 mask quadrant (4 rounds of 16
// coalesced 256B loads, held in flight) into 64 u64 LDS words. Epilogue reads
// broadcast LDS bits -- no global mask access at tile end.
__global__ __launch_bounds__(256) void gemmS(
    const u16* __restrict__ qb, const u16* __restrict__ kb,
    const int* __restrict__ mask, u16* __restrict__ Sdst, int b0)
{
    GEMM_PRE();
    __shared__ u64 maskw[256];          // [wave][row_local]
    const int zb = blockIdx.z;
    const int b = b0 + zb;
    // T1 XCD swizzle: plane nwg=256
    const int hh = blockIdx.y * 16 + blockIdx.x;
    const int sl = (hh & 7) * 32 + (hh >> 3);
    const int m0 = (sl >> 4) * 128, n0 = (sl & 15) * 128;

    {   // mask pack: wave (wm,wn) covers rows m0+wm*64.., cols n0+wn*64..
        const int* mrow = mask + ((size_t)b * S_DIM + m0 + wm * 64) * S_DIM
                               + n0 + wn * 64 + l;
#pragma unroll
        for (int rnd = 0; rnd < 4; ++rnd) {
            int v[16];
#pragma unroll
            for (int i = 0; i < 16; ++i)
                v[i] = mrow[(size_t)(rnd * 16 + i) * S_DIM];
            u64 bb[16];
#pragma unroll
            for (int i = 0; i < 16; ++i)
                bb[i] = __ballot(v[i] > 0);
            if (l == 0) {
#pragma unroll
                for (int i = 0; i < 16; ++i)
                    maskw[w * 64 + rnd * 16 + i] = bb[i];
            }
        }
    }

    const u16* A = qb + (size_t)(b * S_DIM + m0) * 512;
    const u16* B = kb + (size_t)(b * S_DIM + n0) * 512;
    gemm_core<0, 0, 0>(A, 512, B, 512, 512, As, Bs, acc, accS);

    u16* Sb = Sdst + (size_t)zb * S_DIM * S_DIM;
#pragma unroll
    for (int mi = 0; mi < 4; ++mi)
#pragma unroll
        for (int r = 0; r < 4; ++r) {
            const int row = m0 + wm * 64 + mi * 16 + quad * 4 + r;
            const u64 wbits = maskw[w * 64 + mi * 16 + quad * 4 + r];
            const int col0 = n0 + wn * 64 + lane15;
#pragma unroll
            for (int ni = 0; ni < 4; ++ni) {
                const int masked = (int)((wbits >> (lane15 + ni * 16)) & 1);
                const float p = masked ? 0.f : __expf(acc[mi][ni][r] * SCALE);
                Sb[(size_t)row * S_DIM + col0 + ni * 16] = f2h_bits(p);
            }
        }
}

// ---------------- gemmO: out = (S @ Vt) / rowsum(S), phased ----------------
__global__ __launch_bounds__(256) void gemmO(
    const u16* __restrict__ Ssrc, const u16* __restrict__ vt,
    float* __restrict__ outp, int b0)
{
    GEMM_PRE();
    const int zb = blockIdx.z;
    const int b = b0 + zb;
    // T1 XCD swizzle: plane nwg=64
    const int hh = blockIdx.y * 4 + blockIdx.x;
    const int sl = (hh & 7) * 8 + (hh >> 3);
    const int m0 = (sl >> 2) * 128, n0 = (sl & 3) * 128;
    const u16* A = Ssrc + (size_t)zb * S_DIM * S_DIM + (size_t)m0 * S_DIM;
    const u16* B = vt + ((size_t)b * 512 + n0) * 2048;

    gemm_core<1, 0, 0>(A, S_DIM, B, S_DIM, S_DIM, As, Bs, acc, accS);

#pragma unroll
    for (int mi = 0; mi < 4; ++mi)
#pragma unroll
        for (int r = 0; r < 4; ++r) {
            const int row = m0 + wm * 64 + mi * 16 + quad * 4 + r;
            const float inv = 1.f / accS[mi][r];
#pragma unroll
            for (int ni = 0; ni < 4; ++ni) {
                const int col = n0 + wn * 64 + ni * 16 + lane15;
                outp[((size_t)b * S_DIM + row) * E_DIM + col] = acc[mi][ni][r] * inv;
            }
        }
}

extern "C" void kernel_launch(void* const* d_in, const int* in_sizes, int n_in,
                              void* d_out, int out_size, void* d_ws, size_t ws_size,
                              hipStream_t stream) {
    const void* x    = d_in[0];
    const int*  mask = (const int*)d_in[1];
    const void* wq   = d_in[2];
    const void* bq   = d_in[3];
    const void* wk   = d_in[4];
    const void* bk   = d_in[5];
    const void* wv   = d_in[6];
    const void* bv   = d_in[7];

    const size_t MB   = 1ull << 20;
    const size_t QSZ  = (size_t)NROWS * E_DIM;          // u16 elems per Q/K/Vt/xh
    const size_t S_PB = (size_t)S_DIM * S_DIM;          // u16 elems per S batch

    u16* wb   = (u16*)d_ws;                             // 2 MB (weights+bias f16)
    u16* qb   = (u16*)((char*)d_ws + 2 * MB);
    u16* kb   = qb + QSZ;
    u16* vtb  = kb + QSZ;
    u16* xh   = vtb + QSZ;                              // 16.8 MB f16 x (dead after proj)
    u16* sS   = xh;                                     // S scratch aliases xh

    const size_t fixed = 2 * MB + 3 * QSZ * 2;          // 52.4 MB (pre-xh)
    const size_t avail = (ws_size > fixed) ? (ws_size - fixed) : 0;
    const int use_xh = avail >= (QSZ * 2 + 2 * S_PB);   // xh + >=2 S batches
    const size_t availB = avail / (S_PB * 2);
    const int P = (availB >= 8) ? 8 : (availB >= 4) ? 4 : (availB >= 2) ? 2 : 1;

    conv_w<<<dim3(128, 3), 256, 0, stream>>>(wq, wk, wv, bq, bk, bv, wb);

    if (use_xh) {
        conv_x<<<NROWS / 4, 256, 0, stream>>>(x, wq, xh);
        proj_gemm<0><<<dim3(4, 128, 3), 256, 0, stream>>>(xh, wb, qb, kb, vtb);
    } else {
        // small-ws fallback: on-the-fly x conversion; dtype via in_sizes
        // (x fp32 = NROWS*512*4 bytes; 16-bit input = half that).
        if (in_sizes[0] >= (int)(NROWS * 512 * 4))
            proj_gemm<1><<<dim3(4, 128, 3), 256, 0, stream>>>(x, wb, qb, kb, vtb);
        else
            proj_gemm<2><<<dim3(4, 128, 3), 256, 0, stream>>>(x, wb, qb, kb, vtb);
    }

    for (int p = 0; p < 8; p += P) {
        gemmS<<<dim3(16, 16, P), 256, 0, stream>>>(qb, kb, mask, sS, p);
        gemmO<<<dim3(4, 16, P), 256, 0, stream>>>(sS, vtb, (float*)d_out, p);
    }
}

// Round 10
// 198.136 us; speedup vs baseline: 1.0735x; 1.0198x over previous
//
#include <hip/hip_runtime.h>
#include <hip/hip_bf16.h>
#include <hip/hip_fp16.h>

// MHAHead B=8,S=2048,E=512. R14: gemmS -> 256^2 8-wave tile; proj/gemmO = R11.
//   R12 (explicit dbuf) and R13 (BK=64@128^2) both regressed: within the
//   128^2/4-wave tile, any LDS growth costs the occupancy that was hiding
//   latency. Catalog: 256^2/8-wave at the SAME 2-barrier schedule = 655-682 TF
//   (m230/m248) vs our 277 -- 4x MFMA per drain (32/wave/K-half), same staging
//   per thread, granule-XOR LDS layout generalizes verbatim.
//   R14: gemmS only -> 512 thr, tile 256x256, BK=64, acc[8][4],
//        __launch_bounds__(512,2); mask pack 8 rounds/wave (8KB LDS).
//        proj/gemmO revert to R11-exact BK=32 128^2 core.
//   conv_w : weights/biases -> f16 in ws
//   conv_x : x fp32/bf16 -> f16 dense in ws (skipped if ws too small)
//   proj   : uni GEMM 128x128xBK32 (Q,K,Vt), all-gld16 staging
//   gemmS  : S = exp(mask? 0 : Q.K^T*scale) f16, 256^2 core, phased
//   gemmO  : out = (S @ Vt) / rowsum(S), rowsum via all-ones-B MFMA column

typedef unsigned short u16;
typedef unsigned long long u64;
typedef __attribute__((ext_vector_type(8))) short short8;
typedef __attribute__((ext_vector_type(8))) _Float16 half8;
typedef __attribute__((ext_vector_type(4))) float float4v;

#define S_DIM 2048
#define E_DIM 512
#define NROWS (8 * S_DIM)
#define SCALE 0.044194173824159216f

__device__ __forceinline__ float4v mfma16(short8 a, short8 b, float4v c) {
    return __builtin_amdgcn_mfma_f32_16x16x32_f16(
        __builtin_bit_cast(half8, a), __builtin_bit_cast(half8, b), c, 0, 0, 0);
}
__device__ __forceinline__ float bf2f(unsigned int u) {
    union { unsigned int i; float f; } v; v.i = u << 16; return v.f;
}
__device__ __forceinline__ u16 f2h_bits(float f) {
    union { _Float16 h; u16 u; } v; v.h = (_Float16)f; return v.u;
}
__device__ __forceinline__ float h2f(u16 u) {
    union { u16 u; _Float16 h; } v; v.u = u; return (float)v.h;
}
__device__ __forceinline__ int detect_bf16(const void* wp) {
    const u16* w = (const u16*)wp;
    int cnt = 0;
    for (int i = 0; i < 64; ++i) {
        int e = (w[2 * i] >> 7) & 0xff;
        cnt += (e >= 100 && e <= 131) ? 1 : 0;
    }
    return cnt >= 40;
}
__device__ __forceinline__ void load8(const void* base, size_t idx, int isbf, float* f) {
    if (isbf) {
        uint4 v = *(const uint4*)((const u16*)base + idx);
        f[0] = bf2f(v.x & 0xffffu); f[1] = bf2f(v.x >> 16);
        f[2] = bf2f(v.y & 0xffffu); f[3] = bf2f(v.y >> 16);
        f[4] = bf2f(v.z & 0xffffu); f[5] = bf2f(v.z >> 16);
        f[6] = bf2f(v.w & 0xffffu); f[7] = bf2f(v.w >> 16);
    } else {
        const float* p = (const float*)base + idx;
        float4 a = *(const float4*)p;
        float4 b = *(const float4*)(p + 4);
        f[0] = a.x; f[1] = a.y; f[2] = a.z; f[3] = a.w;
        f[4] = b.x; f[5] = b.y; f[6] = b.z; f[7] = b.w;
    }
}
__device__ __forceinline__ float load1(const void* base, size_t idx, int isbf) {
    return isbf ? bf2f(((const u16*)base)[idx]) : ((const float*)base)[idx];
}

// async 16B global -> LDS (per-lane src, wave-uniform LDS base + lane*16)
__device__ __forceinline__ void gld16(const u16* g, u16* l) {
    __builtin_amdgcn_global_load_lds(
        (const __attribute__((address_space(1))) void*)g,
        (__attribute__((address_space(3))) void*)l, 16, 0, 0);
}

// stage one 16B granule into LDS. C=0: f16 global, async gld16.
// C=1: fp32 global -> f16 (reg-staged). C=2: bf16 global -> f16 (reg-staged).
template<int C>
__device__ __forceinline__ void stage(const void* g, size_t off, u16* lds) {
    if constexpr (C == 0) {
        gld16((const u16*)g + off, lds);
    } else if constexpr (C == 1) {
        const float* p = (const float*)g + off;
        float4 a = *(const float4*)p;
        float4 b = *(const float4*)(p + 4);
        union { u16 h[8]; short8 v; } pk;
        pk.h[0] = f2h_bits(a.x); pk.h[1] = f2h_bits(a.y);
        pk.h[2] = f2h_bits(a.z); pk.h[3] = f2h_bits(a.w);
        pk.h[4] = f2h_bits(b.x); pk.h[5] = f2h_bits(b.y);
        pk.h[6] = f2h_bits(b.z); pk.h[7] = f2h_bits(b.w);
        *(short8*)lds = pk.v;
    } else {
        uint4 v = *(const uint4*)((const u16*)g + off);
        unsigned int uu[4] = {v.x, v.y, v.z, v.w};
        union { u16 h[8]; short8 v8; } pk;
#pragma unroll
        for (int j = 0; j < 4; ++j) {
            pk.h[2 * j]     = f2h_bits(bf2f(uu[j] & 0xffffu));
            pk.h[2 * j + 1] = f2h_bits(bf2f(uu[j] >> 16));
        }
        *(short8*)lds = pk.v8;
    }
}

// ---------------- conversion kernels (read inputs, write ws) ----------------
__global__ __launch_bounds__(256) void conv_w(
    const void* w0, const void* w1, const void* w2,
    const void* b0, const void* b1, const void* b2, u16* wb)
{
    const int z = blockIdx.y;
    const void* w = (z == 0) ? w0 : (z == 1) ? w1 : w2;
    const void* bb = (z == 0) ? b0 : (z == 1) ? b1 : b2;
    const int isbf = detect_bf16(w0);
    const size_t idx = ((size_t)blockIdx.x * 256 + threadIdx.x) * 8;
    float f[8];
    load8(w, idx, isbf, f);
    union { u16 h[8]; uint4 v; } pk;
#pragma unroll
    for (int j = 0; j < 8; ++j) pk.h[j] = f2h_bits(f[j]);
    *(uint4*)(wb + (size_t)z * 262144 + idx) = pk.v;
    if (blockIdx.x == 0) {
        u16* bbase = wb + 3 * 262144 + z * 512;
#pragma unroll
        for (int j = 0; j < 2; ++j) {
            int i = threadIdx.x * 2 + j;
            bbase[i] = f2h_bits(load1(bb, i, isbf));
        }
    }
}

// x fp32/bf16 -> f16 dense [16384][512] in ws. One wave per row.
__global__ __launch_bounds__(256) void conv_x(
    const void* x, const void* wq_orig, u16* xh)
{
    const int w = threadIdx.x >> 6, l = threadIdx.x & 63;
    const int row = blockIdx.x * 4 + w;
    union { u16 h[8]; uint4 v; } pk;
    if (detect_bf16(wq_orig)) {
        uint4 v = *(const uint4*)((const u16*)x + (size_t)row * 512 + l * 8);
        unsigned int uu[4] = {v.x, v.y, v.z, v.w};
#pragma unroll
        for (int j = 0; j < 4; ++j) {
            pk.h[2 * j]     = f2h_bits(bf2f(uu[j] & 0xffffu));
            pk.h[2 * j + 1] = f2h_bits(bf2f(uu[j] >> 16));
        }
    } else {
        const float* src = (const float*)x + (size_t)row * 512 + l * 8;
        float4 a = *(const float4*)src;
        float4 b = *(const float4*)(src + 4);
        pk.h[0] = f2h_bits(a.x); pk.h[1] = f2h_bits(a.y);
        pk.h[2] = f2h_bits(a.z); pk.h[3] = f2h_bits(a.w);
        pk.h[4] = f2h_bits(b.x); pk.h[5] = f2h_bits(b.y);
        pk.h[6] = f2h_bits(b.z); pk.h[7] = f2h_bits(b.w);
    }
    *(uint4*)(xh + (size_t)row * 512 + l * 8) = pk.v;
}

// ---------------- 128^2 GEMM core (R11-exact: BK=32, 4 waves) ----------------
// LDS layout: granule(16B) flat = 4*r + (kq ^ ((r>>1)&3))  -> 2-way max conflicts.
template<int ONES, int CA, int CB>
__device__ __forceinline__ void gemm_core(
    const void* __restrict__ A, int sA, const void* __restrict__ B, int sB, int K,
    u16* As, u16* Bs, float4v acc[4][4], float4v accS[4])
{
    const int t = threadIdx.x;
    const int w = t >> 6, l = t & 63;
    const int lane15 = l & 15, quad = l >> 4;
    const int wm = w & 1, wn = w >> 1;

    short8 ones;
#pragma unroll
    for (int j = 0; j < 8; ++j) ones[j] = (short)0x3C00;   // f16 1.0

    for (int kt = 0; kt < K; kt += 32) {
        __syncthreads();
#pragma unroll
        for (int i = 0; i < 2; ++i) {
            const int fg = w * 128 + i * 64 + l;
            const int r = fg >> 2;
            const int kq = (fg & 3) ^ ((r >> 1) & 3);
            stage<CA>(A, (size_t)r * sA + kt + kq * 8, As + fg * 8);
            stage<CB>(B, (size_t)r * sB + kt + kq * 8, Bs + fg * 8);
        }
        __syncthreads();

        short8 af[4], bf[4];
#pragma unroll
        for (int mi = 0; mi < 4; ++mi) {
            const int r = wm * 64 + mi * 16 + lane15;
            af[mi] = *(const short8*)&As[(4 * r + (quad ^ ((r >> 1) & 3))) * 8];
        }
#pragma unroll
        for (int ni = 0; ni < 4; ++ni) {
            const int r = wn * 64 + ni * 16 + lane15;
            bf[ni] = *(const short8*)&Bs[(4 * r + (quad ^ ((r >> 1) & 3))) * 8];
        }
#pragma unroll
        for (int mi = 0; mi < 4; ++mi) {
#pragma unroll
            for (int ni = 0; ni < 4; ++ni)
                acc[mi][ni] = mfma16(af[mi], bf[ni], acc[mi][ni]);
            if (ONES) accS[mi] = mfma16(af[mi], ones, accS[mi]);
        }
    }
}

#define GEMM_PRE()                                                     \
    __shared__ u16 As[4096] __attribute__((aligned(16)));              \
    __shared__ u16 Bs[4096] __attribute__((aligned(16)));              \
    const int t = threadIdx.x;                                         \
    const int w = t >> 6, l = t & 63;                                  \
    const int lane15 = l & 15, quad = l >> 4;                          \
    const int wm = w & 1, wn = w >> 1;                                 \
    (void)l; (void)w;                                                  \
    float4v acc[4][4];                                                 \
    float4v accS[4];                                                   \
    _Pragma("unroll") for (int mi = 0; mi < 4; ++mi) {                 \
        accS[mi] = (float4v){0.f, 0.f, 0.f, 0.f};                      \
        _Pragma("unroll") for (int ni = 0; ni < 4; ++ni)               \
            acc[mi][ni] = (float4v){0.f, 0.f, 0.f, 0.f};               \
    }

// ---------------- 256^2 GEMM core (8 waves 2Mx4N, BK=64, gld16-only) --------
// Per wave: 128x64 output = acc[8][4]. Per K-half(32): 32 MFMA/wave, staging
// identical per-thread to the 128^2 core (fg formula extends to w<8, r<256).
// MFMA split into two mi-halves to cap live af registers.
__device__ __forceinline__ void gemm_core256(
    const u16* __restrict__ A, int sA, const u16* __restrict__ B, int sB, int K,
    u16* As, u16* Bs, float4v acc[8][4])
{
    const int t = threadIdx.x;
    const int w = t >> 6, l = t & 63;
    const int lane15 = l & 15, quad = l >> 4;
    const int wm = w & 1, wn = w >> 1;   // wm in [0,2), wn in [0,4)

    for (int kt = 0; kt < K; kt += 64) {
        __syncthreads();
#pragma unroll
        for (int h = 0; h < 2; ++h)
#pragma unroll
            for (int i = 0; i < 2; ++i) {
                const int fg = w * 128 + i * 64 + l;     // 0..1023
                const int r = fg >> 2;                   // 0..255
                const int kq = (fg & 3) ^ ((r >> 1) & 3);
                gld16(A + (size_t)r * sA + kt + 32 * h + kq * 8,
                      As + h * 8192 + fg * 8);
                gld16(B + (size_t)r * sB + kt + 32 * h + kq * 8,
                      Bs + h * 8192 + fg * 8);
            }
        __syncthreads();

#pragma unroll
        for (int h = 0; h < 2; ++h) {
            const int bo = h * 8192;
            short8 bf[4];
#pragma unroll
            for (int ni = 0; ni < 4; ++ni) {
                const int r = wn * 64 + ni * 16 + lane15;
                bf[ni] = *(const short8*)&Bs[bo + (4 * r + (quad ^ ((r >> 1) & 3))) * 8];
            }
#pragma unroll
            for (int mh = 0; mh < 2; ++mh) {
                short8 af[4];
#pragma unroll
                for (int q4 = 0; q4 < 4; ++q4) {
                    const int r = wm * 128 + (mh * 4 + q4) * 16 + lane15;
                    af[q4] = *(const short8*)&As[bo + (4 * r + (quad ^ ((r >> 1) & 3))) * 8];
                }
#pragma unroll
                for (int q4 = 0; q4 < 4; ++q4)
#pragma unroll
                    for (int ni = 0; ni < 4; ++ni)
                        acc[mh * 4 + q4][ni] = mfma16(af[q4], bf[ni], acc[mh * 4 + q4][ni]);
            }
        }
    }
}

// ---------------- proj: Q, K, Vt (pure GEMM, no mask; R11-exact) -------------
// XM: 0 = xh f16 (gld16 both sides), 1 = x fp32, 2 = x bf16.
template<int XM>
__global__ __launch_bounds__(256) void proj_gemm(
    const void* __restrict__ xsrc, const u16* __restrict__ wb,
    u16* __restrict__ qb, u16* __restrict__ kb, u16* __restrict__ vt)
{
    GEMM_PRE();
    const int z = blockIdx.z;
    // T1 XCD swizzle within the 512-plane (nwg %8==0, bijective)
    const int hh = blockIdx.y * 4 + blockIdx.x;
    const int sl = (hh & 7) * 64 + (hh >> 3);
    const int ty = sl >> 2, tx = sl & 3;
    const u16* bias = wb + 3 * 262144 + z * 512;

    int m0, n0;
    if (z < 2) { m0 = ty * 128; n0 = tx * 128; }
    else       { m0 = tx * 128; n0 = ty * 128; }

    if (z < 2) {
        const void* B = wb + (size_t)z * 262144 + (size_t)n0 * 512;
        const void* A = (XM == 1)
            ? (const void*)((const float*)xsrc + (size_t)m0 * 512)
            : (const void*)((const u16*)xsrc + (size_t)m0 * 512);
        gemm_core<0, XM == 0 ? 0 : XM, 0>(A, 512, B, 512, 512, As, Bs, acc, accS);
    } else {
        const void* A = wb + (size_t)2 * 262144 + (size_t)m0 * 512;
        const void* B = (XM == 1)
            ? (const void*)((const float*)xsrc + (size_t)n0 * 512)
            : (const void*)((const u16*)xsrc + (size_t)n0 * 512);
        gemm_core<0, 0, XM == 0 ? 0 : XM>(A, 512, B, 512, 512, As, Bs, acc, accS);
    }

    if (z < 2) {
        u16* dst = z ? kb : qb;
        float bcol[4];
#pragma unroll
        for (int ni = 0; ni < 4; ++ni)
            bcol[ni] = h2f(bias[n0 + wn * 64 + ni * 16 + lane15]);
#pragma unroll
        for (int mi = 0; mi < 4; ++mi)
#pragma unroll
            for (int ni = 0; ni < 4; ++ni)
#pragma unroll
                for (int r = 0; r < 4; ++r) {
                    const int row = m0 + wm * 64 + mi * 16 + quad * 4 + r;
                    const int col = n0 + wn * 64 + ni * 16 + lane15;
                    dst[(size_t)row * 512 + col] = f2h_bits(acc[mi][ni][r] + bcol[ni]);
                }
    } else {
#pragma unroll
        for (int mi = 0; mi < 4; ++mi)
#pragma unroll
            for (int r = 0; r < 4; ++r) {
                const int e = m0 + wm * 64 + mi * 16 + quad * 4 + r;      // 0..511
                const float bias_e = h2f(bias[e]);
#pragma unroll
                for (int ni = 0; ni < 4; ++ni) {
                    const int tok = n0 + wn * 64 + ni * 16 + lane15;
                    vt[((size_t)(tok >> 11) * 512 + e) * 2048 + (tok & 2047)] =
                        f2h_bits(acc[mi][ni][r] + bias_e);
                }
            }
    }
}

// ---------------- gemmS: S = exp(masked(Q.K^T * scale)) f16, 256^2, phased ---
// 512 threads, tile 256x256, BK=64. Per wave: 128x64 output + its own 128-row
// mask-bit window packed into LDS (8 rounds x 16 coalesced 256B loads).
__global__ __launch_bounds__(512, 2) void gemmS(
    const u16* __restrict__ qb, const u16* __restrict__ kb,
    const int* __restrict__ mask, u16* __restrict__ Sdst, int b0)
{
    __shared__ u16 As[16384] __attribute__((aligned(16)));
    __shared__ u16 Bs[16384] __attribute__((aligned(16)));
    __shared__ u64 maskw[1024];         // [wave][128 rows]
    const int t = threadIdx.x;
    const int w = t >> 6, l = t & 63;
    const int lane15 = l & 15, quad = l >> 4;
    const int wm = w & 1, wn = w >> 1;

    const int zb = blockIdx.z;
    const int b = b0 + zb;
    // T1 XCD swizzle: plane nwg=64 (8x8 tiles of 256^2)
    const int hh = blockIdx.y * 8 + blockIdx.x;
    const int sl = (hh & 7) * 8 + (hh >> 3);
    const int m0 = (sl >> 3) * 256, n0 = (sl & 7) * 256;

    {   // mask pack: wave covers rows m0+wm*128+[0,128), cols n0+wn*64+l
        const int* mrow = mask + ((size_t)b * S_DIM + m0 + wm * 128) * S_DIM
                               + n0 + wn * 64 + l;
#pragma unroll
        for (int rnd = 0; rnd < 8; ++rnd) {
            int v[16];
#pragma unroll
            for (int i = 0; i < 16; ++i)
                v[i] = mrow[(size_t)(rnd * 16 + i) * S_DIM];
            u64 bb[16];
#pragma unroll
            for (int i = 0; i < 16; ++i)
                bb[i] = __ballot(v[i] > 0);
            if (l == 0) {
#pragma unroll
                for (int i = 0; i < 16; ++i)
                    maskw[w * 128 + rnd * 16 + i] = bb[i];
            }
        }
    }

    float4v acc[8][4];
#pragma unroll
    for (int mi = 0; mi < 8; ++mi)
#pragma unroll
        for (int ni = 0; ni < 4; ++ni)
            acc[mi][ni] = (float4v){0.f, 0.f, 0.f, 0.f};

    const u16* A = qb + (size_t)(b * S_DIM + m0) * 512;
    const u16* B = kb + (size_t)(b * S_DIM + n0) * 512;
    gemm_core256(A, 512, B, 512, 512, As, Bs, acc);

    u16* Sb = Sdst + (size_t)zb * S_DIM * S_DIM;
#pragma unroll
    for (int mi = 0; mi < 8; ++mi)
#pragma unroll
        for (int r = 0; r < 4; ++r) {
            const int rl = mi * 16 + quad * 4 + r;        // 0..127 within wave
            const int row = m0 + wm * 128 + rl;
            const u64 wbits = maskw[w * 128 + rl];
            const int col0 = n0 + wn * 64 + lane15;
#pragma unroll
            for (int ni = 0; ni < 4; ++ni) {
                const int masked = (int)((wbits >> (lane15 + ni * 16)) & 1);
                const float p = masked ? 0.f : __expf(acc[mi][ni][r] * SCALE);
                Sb[(size_t)row * S_DIM + col0 + ni * 16] = f2h_bits(p);
            }
        }
}

// ---------------- gemmO: out = (S @ Vt) / rowsum(S), phased (R11-exact) ------
__global__ __launch_bounds__(256) void gemmO(
    const u16* __restrict__ Ssrc, const u16* __restrict__ vt,
    float* __restrict__ outp, int b0)
{
    GEMM_PRE();
    const int zb = blockIdx.z;
    const int b = b0 + zb;
    // T1 XCD swizzle: plane nwg=64
    const int hh = blockIdx.y * 4 + blockIdx.x;
    const int sl = (hh & 7) * 8 + (hh >> 3);
    const int m0 = (sl >> 2) * 128, n0 = (sl & 3) * 128;
    const u16* A = Ssrc + (size_t)zb * S_DIM * S_DIM + (size_t)m0 * S_DIM;
    const u16* B = vt + ((size_t)b * 512 + n0) * 2048;

    gemm_core<1, 0, 0>(A, S_DIM, B, S_DIM, S_DIM, As, Bs, acc, accS);

#pragma unroll
    for (int mi = 0; mi < 4; ++mi)
#pragma unroll
        for (int r = 0; r < 4; ++r) {
            const int row = m0 + wm * 64 + mi * 16 + quad * 4 + r;
            const float inv = 1.f / accS[mi][r];
#pragma unroll
            for (int ni = 0; ni < 4; ++ni) {
                const int col = n0 + wn * 64 + ni * 16 + lane15;
                outp[((size_t)b * S_DIM + row) * E_DIM + col] = acc[mi][ni][r] * inv;
            }
        }
}

extern "C" void kernel_launch(void* const* d_in, const int* in_sizes, int n_in,
                              void* d_out, int out_size, void* d_ws, size_t ws_size,
                              hipStream_t stream) {
    const void* x    = d_in[0];
    const int*  mask = (const int*)d_in[1];
    const void* wq   = d_in[2];
    const void* bq   = d_in[3];
    const void* wk   = d_in[4];
    const void* bk   = d_in[5];
    const void* wv   = d_in[6];
    const void* bv   = d_in[7];

    const size_t MB   = 1ull << 20;
    const size_t QSZ  = (size_t)NROWS * E_DIM;          // u16 elems per Q/K/Vt/xh
    const size_t S_PB = (size_t)S_DIM * S_DIM;          // u16 elems per S batch

    u16* wb   = (u16*)d_ws;                             // 2 MB (weights+bias f16)
    u16* qb   = (u16*)((char*)d_ws + 2 * MB);
    u16* kb   = qb + QSZ;
    u16* vtb  = kb + QSZ;
    u16* xh   = vtb + QSZ;                              // 16.8 MB f16 x (dead after proj)
    u16* sS   = xh;                                     // S scratch aliases xh

    const size_t fixed = 2 * MB + 3 * QSZ * 2;          // 52.4 MB (pre-xh)
    const size_t avail = (ws_size > fixed) ? (ws_size - fixed) : 0;
    const int use_xh = avail >= (QSZ * 2 + 2 * S_PB);   // xh + >=2 S batches
    const size_t availB = avail / (S_PB * 2);
    const int P = (availB >= 8) ? 8 : (availB >= 4) ? 4 : (availB >= 2) ? 2 : 1;

    conv_w<<<dim3(128, 3), 256, 0, stream>>>(wq, wk, wv, bq, bk, bv, wb);

    if (use_xh) {
        conv_x<<<NROWS / 4, 256, 0, stream>>>(x, wq, xh);
        proj_gemm<0><<<dim3(4, 128, 3), 256, 0, stream>>>(xh, wb, qb, kb, vtb);
    } else {
        // small-ws fallback: on-the-fly x conversion; dtype via in_sizes
        // (x fp32 = NROWS*512*4 bytes; 16-bit input = half that).
        if (in_sizes[0] >= (int)(NROWS * 512 * 4))
            proj_gemm<1><<<dim3(4, 128, 3), 256, 0, stream>>>(x, wb, qb, kb, vtb);
        else
            proj_gemm<2><<<dim3(4, 128, 3), 256, 0, stream>>>(x, wb, qb, kb, vtb);
    }

    for (int p = 0; p < 8; p += P) {
        gemmS<<<dim3(8, 8, P), 512, 0, stream>>>(qb, kb, mask, sS, p);
        gemmO<<<dim3(4, 16, P), 256, 0, stream>>>(sS, vtb, (float*)d_out, p);
    }
}

// Round 11
// 197.370 us; speedup vs baseline: 1.0777x; 1.0039x over previous
//
#include <hip/hip_runtime.h>
#include <hip/hip_bf16.h>
#include <hip/hip_fp16.h>

// MHAHead B=8,S=2048,E=512. R15: R11 structure + TILED operand storage.
//   R12-R14 post-mortem: three different K-loop structures all ~124-132us,
//   MfmaUtil pinned ~10.5%; warm==cold dur. Bottleneck is NOT drains/latency:
//   each gld16 reads 16 scattered 64B segments (row-major staging) -> ~256
//   VMEM transactions per block-iter serialize on the CU's memory pipe.
//   R15: all GEMM operands (xh, wb, Q, K, S, Vt) stored in LDS-granule tile
//   order by their PRODUCERS (epilogues already scalar-store); every gld16
//   becomes 1KB fully contiguous. Compute side byte-identical to R11.
//   Tile = [128 rows][32 u16 K-cols] = 512 granules(16B); granule(rr,kq) at
//   index 4*rr + (kq ^ ((rr>>1)&3)); tile t of row-block RB at
//   ((RB*NT + t) * 512) granules. NT = K/32 (16 for E=512, 64 for S=2048).
//   conv_w : weights/biases -> f16 tiled in ws
//   conv_x : x fp32/bf16 -> f16 tiled in ws (skipped if ws too small)
//   proj   : uni GEMM 128x128xBK32 (Q,K,Vt tiled out), all-gld16 staging
//   gemmS  : S = exp(mask? 0 : Q.K^T*scale) f16 tiled out, in-kernel mask pack
//   gemmO  : out = (S @ Vt) / rowsum(S), rowsum via all-ones-B MFMA column

typedef unsigned short u16;
typedef unsigned long long u64;
typedef __attribute__((ext_vector_type(8))) short short8;
typedef __attribute__((ext_vector_type(8))) _Float16 half8;
typedef __attribute__((ext_vector_type(4))) float float4v;

#define S_DIM 2048
#define E_DIM 512
#define NROWS (8 * S_DIM)
#define SCALE 0.044194173824159216f

__device__ __forceinline__ float4v mfma16(short8 a, short8 b, float4v c) {
    return __builtin_amdgcn_mfma_f32_16x16x32_f16(
        __builtin_bit_cast(half8, a), __builtin_bit_cast(half8, b), c, 0, 0, 0);
}
__device__ __forceinline__ float bf2f(unsigned int u) {
    union { unsigned int i; float f; } v; v.i = u << 16; return v.f;
}
__device__ __forceinline__ u16 f2h_bits(float f) {
    union { _Float16 h; u16 u; } v; v.h = (_Float16)f; return v.u;
}
__device__ __forceinline__ float h2f(u16 u) {
    union { u16 u; _Float16 h; } v; v.u = u; return (float)v.h;
}
// tiled u16 index for element (row, col) in a [rows][K] matrix with NT=K/32 tiles
__device__ __forceinline__ size_t tidx(int row, int col, int NT) {
    const int rr = row & 127;
    const int g = 4 * rr + (((col & 31) >> 3) ^ ((rr >> 1) & 3));
    return ((size_t)((row >> 7) * NT + (col >> 5)) * 512 + g) * 8 + (col & 7);
}
__device__ __forceinline__ int detect_bf16(const void* wp) {
    const u16* w = (const u16*)wp;
    int cnt = 0;
    for (int i = 0; i < 64; ++i) {
        int e = (w[2 * i] >> 7) & 0xff;
        cnt += (e >= 100 && e <= 131) ? 1 : 0;
    }
    return cnt >= 40;
}
__device__ __forceinline__ void load8(const void* base, size_t idx, int isbf, float* f) {
    if (isbf) {
        uint4 v = *(const uint4*)((const u16*)base + idx);
        f[0] = bf2f(v.x & 0xffffu); f[1] = bf2f(v.x >> 16);
        f[2] = bf2f(v.y & 0xffffu); f[3] = bf2f(v.y >> 16);
        f[4] = bf2f(v.z & 0xffffu); f[5] = bf2f(v.z >> 16);
        f[6] = bf2f(v.w & 0xffffu); f[7] = bf2f(v.w >> 16);
    } else {
        const float* p = (const float*)base + idx;
        float4 a = *(const float4*)p;
        float4 b = *(const float4*)(p + 4);
        f[0] = a.x; f[1] = a.y; f[2] = a.z; f[3] = a.w;
        f[4] = b.x; f[5] = b.y; f[6] = b.z; f[7] = b.w;
    }
}
__device__ __forceinline__ float load1(const void* base, size_t idx, int isbf) {
    return isbf ? bf2f(((const u16*)base)[idx]) : ((const float*)base)[idx];
}

// async 16B global -> LDS (per-lane src, wave-uniform LDS base + lane*16)
__device__ __forceinline__ void gld16(const u16* g, u16* l) {
    __builtin_amdgcn_global_load_lds(
        (const __attribute__((address_space(1))) void*)g,
        (__attribute__((address_space(3))) void*)l, 16, 0, 0);
}

// row-major staging fallback (fp32/bf16 x input): reg-staged convert
template<int C>
__device__ __forceinline__ void stage(const void* g, size_t off, u16* lds) {
    if constexpr (C == 1) {
        const float* p = (const float*)g + off;
        float4 a = *(const float4*)p;
        float4 b = *(const float4*)(p + 4);
        union { u16 h[8]; short8 v; } pk;
        pk.h[0] = f2h_bits(a.x); pk.h[1] = f2h_bits(a.y);
        pk.h[2] = f2h_bits(a.z); pk.h[3] = f2h_bits(a.w);
        pk.h[4] = f2h_bits(b.x); pk.h[5] = f2h_bits(b.y);
        pk.h[6] = f2h_bits(b.z); pk.h[7] = f2h_bits(b.w);
        *(short8*)lds = pk.v;
    } else {
        uint4 v = *(const uint4*)((const u16*)g + off);
        unsigned int uu[4] = {v.x, v.y, v.z, v.w};
        union { u16 h[8]; short8 v8; } pk;
#pragma unroll
        for (int j = 0; j < 4; ++j) {
            pk.h[2 * j]     = f2h_bits(bf2f(uu[j] & 0xffffu));
            pk.h[2 * j + 1] = f2h_bits(bf2f(uu[j] >> 16));
        }
        *(short8*)lds = pk.v8;
    }
}

// ---------------- conversion kernels (read inputs, write ws tiled) ----------
__global__ __launch_bounds__(256) void conv_w(
    const void* w0, const void* w1, const void* w2,
    const void* b0, const void* b1, const void* b2, u16* wb)
{
    const int z = blockIdx.y;
    const void* w = (z == 0) ? w0 : (z == 1) ? w1 : w2;
    const void* bb = (z == 0) ? b0 : (z == 1) ? b1 : b2;
    const int isbf = detect_bf16(w0);
    const size_t idx = ((size_t)blockIdx.x * 256 + threadIdx.x) * 8;
    const int n = (int)(idx >> 9), kk = (int)(idx & 511);
    float f[8];
    load8(w, idx, isbf, f);
    union { u16 h[8]; uint4 v; } pk;
#pragma unroll
    for (int j = 0; j < 8; ++j) pk.h[j] = f2h_bits(f[j]);
    *(uint4*)(wb + (size_t)z * 262144 + tidx(n, kk, 16)) = pk.v;
    if (blockIdx.x == 0) {
        u16* bbase = wb + 3 * 262144 + z * 512;
#pragma unroll
        for (int j = 0; j < 2; ++j) {
            int i = threadIdx.x * 2 + j;
            bbase[i] = f2h_bits(load1(bb, i, isbf));
        }
    }
}

// x fp32/bf16 -> f16 TILED [RB 128][16 tiles][512 granules] in ws.
__global__ __launch_bounds__(256) void conv_x(
    const void* x, const void* wq_orig, u16* xh)
{
    const int w = threadIdx.x >> 6, l = threadIdx.x & 63;
    const int row = blockIdx.x * 4 + w;
    union { u16 h[8]; uint4 v; } pk;
    if (detect_bf16(wq_orig)) {
        uint4 v = *(const uint4*)((const u16*)x + (size_t)row * 512 + l * 8);
        unsigned int uu[4] = {v.x, v.y, v.z, v.w};
#pragma unroll
        for (int j = 0; j < 4; ++j) {
            pk.h[2 * j]     = f2h_bits(bf2f(uu[j] & 0xffffu));
            pk.h[2 * j + 1] = f2h_bits(bf2f(uu[j] >> 16));
        }
    } else {
        const float* src = (const float*)x + (size_t)row * 512 + l * 8;
        float4 a = *(const float4*)src;
        float4 b = *(const float4*)(src + 4);
        pk.h[0] = f2h_bits(a.x); pk.h[1] = f2h_bits(a.y);
        pk.h[2] = f2h_bits(a.z); pk.h[3] = f2h_bits(a.w);
        pk.h[4] = f2h_bits(b.x); pk.h[5] = f2h_bits(b.y);
        pk.h[6] = f2h_bits(b.z); pk.h[7] = f2h_bits(b.w);
    }
    *(uint4*)(xh + tidx(row, l * 8, 16)) = pk.v;
}

// ---------------- shared GEMM core (R11 schedule, tiled gld16 staging) ------
// 128x128 tile, BK=32, 4 waves. CA/CB: 0 = tiled f16 (contiguous 1KB gld16),
// 1 = fp32 row-major reg-staged, 2 = bf16 row-major reg-staged.
template<int ONES, int CA, int CB>
__device__ __forceinline__ void gemm_core(
    const void* __restrict__ A, int sA, const void* __restrict__ B, int sB, int K,
    u16* As, u16* Bs, float4v acc[4][4], float4v accS[4])
{
    const int t = threadIdx.x;
    const int w = t >> 6, l = t & 63;
    const int lane15 = l & 15, quad = l >> 4;
    const int wm = w & 1, wn = w >> 1;

    short8 ones;
#pragma unroll
    for (int j = 0; j < 8; ++j) ones[j] = (short)0x3C00;   // f16 1.0

    for (int kt = 0; kt < K; kt += 32) {
        const int kti = kt >> 5;
        __syncthreads();
#pragma unroll
        for (int i = 0; i < 2; ++i) {
            const int fg = w * 128 + i * 64 + l;
            const int r = fg >> 2;
            const int kq = (fg & 3) ^ ((r >> 1) & 3);
            if constexpr (CA == 0)
                gld16((const u16*)A + (size_t)kti * 4096 + fg * 8, As + fg * 8);
            else
                stage<CA>(A, (size_t)r * sA + kt + kq * 8, As + fg * 8);
            if constexpr (CB == 0)
                gld16((const u16*)B + (size_t)kti * 4096 + fg * 8, Bs + fg * 8);
            else
                stage<CB>(B, (size_t)r * sB + kt + kq * 8, Bs + fg * 8);
        }
        __syncthreads();

        short8 af[4], bf[4];
#pragma unroll
        for (int mi = 0; mi < 4; ++mi) {
            const int r = wm * 64 + mi * 16 + lane15;
            af[mi] = *(const short8*)&As[(4 * r + (quad ^ ((r >> 1) & 3))) * 8];
        }
#pragma unroll
        for (int ni = 0; ni < 4; ++ni) {
            const int r = wn * 64 + ni * 16 + lane15;
            bf[ni] = *(const short8*)&Bs[(4 * r + (quad ^ ((r >> 1) & 3))) * 8];
        }
#pragma unroll
        for (int mi = 0; mi < 4; ++mi) {
#pragma unroll
            for (int ni = 0; ni < 4; ++ni)
                acc[mi][ni] = mfma16(af[mi], bf[ni], acc[mi][ni]);
            if (ONES) accS[mi] = mfma16(af[mi], ones, accS[mi]);
        }
    }
}

#define GEMM_PRE()                                                     \
    __shared__ u16 As[4096] __attribute__((aligned(16)));              \
    __shared__ u16 Bs[4096] __attribute__((aligned(16)));              \
    const int t = threadIdx.x;                                         \
    const int w = t >> 6, l = t & 63;                                  \
    const int lane15 = l & 15, quad = l >> 4;                          \
    const int wm = w & 1, wn = w >> 1;                                 \
    (void)l; (void)w;                                                  \
    float4v acc[4][4];                                                 \
    float4v accS[4];                                                   \
    _Pragma("unroll") for (int mi = 0; mi < 4; ++mi) {                 \
        accS[mi] = (float4v){0.f, 0.f, 0.f, 0.f};                      \
        _Pragma("unroll") for (int ni = 0; ni < 4; ++ni)               \
            acc[mi][ni] = (float4v){0.f, 0.f, 0.f, 0.f};               \
    }

// ---------------- proj: Q, K, Vt (outputs tiled) ----------------
// XM: 0 = xh tiled f16, 1 = x fp32 row-major, 2 = x bf16 row-major.
template<int XM>
__global__ __launch_bounds__(256) void proj_gemm(
    const void* __restrict__ xsrc, const u16* __restrict__ wb,
    u16* __restrict__ qb, u16* __restrict__ kb, u16* __restrict__ vt)
{
    GEMM_PRE();
    const int z = blockIdx.z;
    // T1 XCD swizzle within the 512-plane (nwg %8==0, bijective)
    const int hh = blockIdx.y * 4 + blockIdx.x;
    const int sl = (hh & 7) * 64 + (hh >> 3);
    const int ty = sl >> 2, tx = sl & 3;
    const u16* bias = wb + 3 * 262144 + z * 512;

    int m0, n0;
    if (z < 2) { m0 = ty * 128; n0 = tx * 128; }
    else       { m0 = tx * 128; n0 = ty * 128; }

    if (z < 2) {
        const void* B = wb + (size_t)z * 262144 + (size_t)(n0 >> 7) * 16 * 4096;
        if (XM == 0) {
            const void* A = (const u16*)xsrc + (size_t)(m0 >> 7) * 16 * 4096;
            gemm_core<0, 0, 0>(A, 512, B, 512, 512, As, Bs, acc, accS);
        } else if (XM == 1) {
            const void* A = (const float*)xsrc + (size_t)m0 * 512;
            gemm_core<0, 1, 0>(A, 512, B, 512, 512, As, Bs, acc, accS);
        } else {
            const void* A = (const u16*)xsrc + (size_t)m0 * 512;
            gemm_core<0, 2, 0>(A, 512, B, 512, 512, As, Bs, acc, accS);
        }
    } else {
        const void* A = wb + (size_t)2 * 262144 + (size_t)(m0 >> 7) * 16 * 4096;
        if (XM == 0) {
            const void* B = (const u16*)xsrc + (size_t)(n0 >> 7) * 16 * 4096;
            gemm_core<0, 0, 0>(A, 512, B, 512, 512, As, Bs, acc, accS);
        } else if (XM == 1) {
            const void* B = (const float*)xsrc + (size_t)n0 * 512;
            gemm_core<0, 0, 1>(A, 512, B, 512, 512, As, Bs, acc, accS);
        } else {
            const void* B = (const u16*)xsrc + (size_t)n0 * 512;
            gemm_core<0, 0, 2>(A, 512, B, 512, 512, As, Bs, acc, accS);
        }
    }

    if (z < 2) {
        u16* dst = z ? kb : qb;                 // tiled [rows/128][16][512]g
        float bcol[4];
#pragma unroll
        for (int ni = 0; ni < 4; ++ni)
            bcol[ni] = h2f(bias[n0 + wn * 64 + ni * 16 + lane15]);
#pragma unroll
        for (int mi = 0; mi < 4; ++mi)
#pragma unroll
            for (int ni = 0; ni < 4; ++ni)
#pragma unroll
                for (int r = 0; r < 4; ++r) {
                    const int row = m0 + wm * 64 + mi * 16 + quad * 4 + r;
                    const int col = n0 + wn * 64 + ni * 16 + lane15;
                    dst[tidx(row, col, 16)] = f2h_bits(acc[mi][ni][r] + bcol[ni]);
                }
    } else {
        // Vt tiled per batch: [b][4 RBe][64 T][512]g ; rows = e, K = token
#pragma unroll
        for (int mi = 0; mi < 4; ++mi)
#pragma unroll
            for (int r = 0; r < 4; ++r) {
                const int e = m0 + wm * 64 + mi * 16 + quad * 4 + r;      // 0..511
                const float bias_e = h2f(bias[e]);
#pragma unroll
                for (int ni = 0; ni < 4; ++ni) {
                    const int tok = n0 + wn * 64 + ni * 16 + lane15;
                    const int b = tok >> 11, kk = tok & 2047;
                    vt[(size_t)b * 1048576 + tidx(e, kk, 64)] =
                        f2h_bits(acc[mi][ni][r] + bias_e);
                }
            }
    }
}

// ---------------- gemmS: S = exp(masked(Q.K^T * scale)) f16 tiled, phased ----
__global__ __launch_bounds__(256) void gemmS(
    const u16* __restrict__ qb, const u16* __restrict__ kb,
    const int* __restrict__ mask, u16* __restrict__ Sdst, int b0)
{
    GEMM_PRE();
    __shared__ u64 maskw[256];          // [wave][row_local]
    const int zb = blockIdx.z;
    const int b = b0 + zb;
    // T1 XCD swizzle: plane nwg=256
    const int hh = blockIdx.y * 16 + blockIdx.x;
    const int sl = (hh & 7) * 32 + (hh >> 3);
    const int m0 = (sl >> 4) * 128, n0 = (sl & 15) * 128;

    {   // mask pack: wave (wm,wn) covers rows m0+wm*64.., cols n0+wn*64..
        const int* mrow = mask + ((size_t)b * S_DIM + m0 + wm * 64) * S_DIM
                               + n0 + wn * 64 + l;
#pragma unroll
        for (int rnd = 0; rnd < 4; ++rnd) {
            int v[16];
#pragma unroll
            for (int i = 0; i < 16; ++i)
                v[i] = mrow[(size_t)(rnd * 16 + i) * S_DIM];
            u64 bb[16];
#pragma unroll
            for (int i = 0; i < 16; ++i)
                bb[i] = __ballot(v[i] > 0);
            if (l == 0) {
#pragma unroll
                for (int i = 0; i < 16; ++i)
                    maskw[w * 64 + rnd * 16 + i] = bb[i];
            }
        }
    }

    const u16* A = qb + (size_t)((b * S_DIM + m0) >> 7) * 16 * 4096;
    const u16* B = kb + (size_t)((b * S_DIM + n0) >> 7) * 16 * 4096;
    gemm_core<0, 0, 0>(A, 512, B, 512, 512, As, Bs, acc, accS);

    u16* Sb = Sdst + (size_t)zb * 4194304;      // tiled [16 RB][64 T][512]g
#pragma unroll
    for (int mi = 0; mi < 4; ++mi)
#pragma unroll
        for (int r = 0; r < 4; ++r) {
            const int row = m0 + wm * 64 + mi * 16 + quad * 4 + r;
            const u64 wbits = maskw[w * 64 + mi * 16 + quad * 4 + r];
            const int col0 = n0 + wn * 64 + lane15;
#pragma unroll
            for (int ni = 0; ni < 4; ++ni) {
                const int masked = (int)((wbits >> (lane15 + ni * 16)) & 1);
                const float p = masked ? 0.f : __expf(acc[mi][ni][r] * SCALE);
                Sb[tidx(row, col0 + ni * 16, 64)] = f2h_bits(p);
            }
        }
}

// ---------------- gemmO: out = (S @ Vt) / rowsum(S), phased ----------------
__global__ __launch_bounds__(256) void gemmO(
    const u16* __restrict__ Ssrc, const u16* __restrict__ vt,
    float* __restrict__ outp, int b0)
{
    GEMM_PRE();
    const int zb = blockIdx.z;
    const int b = b0 + zb;
    // T1 XCD swizzle: plane nwg=64
    const int hh = blockIdx.y * 4 + blockIdx.x;
    const int sl = (hh & 7) * 8 + (hh >> 3);
    const int m0 = (sl >> 2) * 128, n0 = (sl & 3) * 128;
    const u16* A = Ssrc + (size_t)zb * 4194304 + (size_t)(m0 >> 7) * 64 * 4096;
    const u16* B = vt + (size_t)b * 1048576 + (size_t)(n0 >> 7) * 64 * 4096;

    gemm_core<1, 0, 0>(A, S_DIM, B, S_DIM, S_DIM, As, Bs, acc, accS);

#pragma unroll
    for (int mi = 0; mi < 4; ++mi)
#pragma unroll
        for (int r = 0; r < 4; ++r) {
            const int row = m0 + wm * 64 + mi * 16 + quad * 4 + r;
            const float inv = 1.f / accS[mi][r];
#pragma unroll
            for (int ni = 0; ni < 4; ++ni) {
                const int col = n0 + wn * 64 + ni * 16 + lane15;
                outp[((size_t)b * S_DIM + row) * E_DIM + col] = acc[mi][ni][r] * inv;
            }
        }
}

extern "C" void kernel_launch(void* const* d_in, const int* in_sizes, int n_in,
                              void* d_out, int out_size, void* d_ws, size_t ws_size,
                              hipStream_t stream) {
    const void* x    = d_in[0];
    const int*  mask = (const int*)d_in[1];
    const void* wq   = d_in[2];
    const void* bq   = d_in[3];
    const void* wk   = d_in[4];
    const void* bk   = d_in[5];
    const void* wv   = d_in[6];
    const void* bv   = d_in[7];

    const size_t MB   = 1ull << 20;
    const size_t QSZ  = (size_t)NROWS * E_DIM;          // u16 elems per Q/K/Vt/xh
    const size_t S_PB = (size_t)S_DIM * S_DIM;          // u16 elems per S batch

    u16* wb   = (u16*)d_ws;                             // 2 MB (weights+bias f16)
    u16* qb   = (u16*)((char*)d_ws + 2 * MB);
    u16* kb   = qb + QSZ;
    u16* vtb  = kb + QSZ;
    u16* xh   = vtb + QSZ;                              // 16.8 MB f16 x (dead after proj)
    u16* sS   = xh;                                     // S scratch aliases xh

    const size_t fixed = 2 * MB + 3 * QSZ * 2;          // 52.4 MB (pre-xh)
    const size_t avail = (ws_size > fixed) ? (ws_size - fixed) : 0;
    const int use_xh = avail >= (QSZ * 2 + 2 * S_PB);   // xh + >=2 S batches
    const size_t availB = avail / (S_PB * 2);
    const int P = (availB >= 8) ? 8 : (availB >= 4) ? 4 : (availB >= 2) ? 2 : 1;

    conv_w<<<dim3(128, 3), 256, 0, stream>>>(wq, wk, wv, bq, bk, bv, wb);

    if (use_xh) {
        conv_x<<<NROWS / 4, 256, 0, stream>>>(x, wq, xh);
        proj_gemm<0><<<dim3(4, 128, 3), 256, 0, stream>>>(xh, wb, qb, kb, vtb);
    } else {
        // small-ws fallback: on-the-fly x conversion; dtype via in_sizes
        // (x fp32 = NROWS*512*4 bytes; 16-bit input = half that).
        if (in_sizes[0] >= (int)(NROWS * 512 * 4))
            proj_gemm<1><<<dim3(4, 128, 3), 256, 0, stream>>>(x, wb, qb, kb, vtb);
        else
            proj_gemm<2><<<dim3(4, 128, 3), 256, 0, stream>>>(x, wb, qb, kb, vtb);
    }

    for (int p = 0; p < 8; p += P) {
        gemmS<<<dim3(16, 16, P), 256, 0, stream>>>(qb, kb, mask, sS, p);
        gemmO<<<dim3(4, 16, P), 256, 0, stream>>>(sS, vtb, (float*)d_out, p);
    }
}